// Round 13
// baseline (127.604 us; speedup 1.0000x reference)
//
#include <hip/hip_runtime.h>
#include <hip/hip_bf16.h>

#define Bdim 16
#define Cdim 512
#define Mdim 256
#define Ndim 4096

typedef short bf16x8 __attribute__((ext_vector_type(8)));
typedef float f32x4 __attribute__((ext_vector_type(4)));
typedef unsigned short us8 __attribute__((ext_vector_type(8)));
typedef unsigned short us4 __attribute__((ext_vector_type(4)));

// round-half-up f32 -> bf16 (tie bias only vs RNE)
__device__ __forceinline__ unsigned short f2b(float f) {
  union { float f; unsigned int u; } v; v.f = f;
  return (unsigned short)((v.u + 0x8000u) >> 16);
}
__device__ __forceinline__ float b2f(unsigned short h) {
  union { unsigned int u; float f; } v; v.u = ((unsigned int)h) << 16;
  return v.f;
}

// ---------------- K0: one-time Wk,Wv f32 -> bf16 (512 KB total) -----------
__global__ __launch_bounds__(256) void k0_convert(
    const float* __restrict__ gWk, const float* __restrict__ gWv,
    unsigned short* __restrict__ oWk, unsigned short* __restrict__ oWv) {
  const int i = (blockIdx.x * 256 + threadIdx.x) * 4;
  f32x4 a = *reinterpret_cast<const f32x4*>(gWk + i);
  f32x4 b = *reinterpret_cast<const f32x4*>(gWv + i);
  us4 ha, hb;
#pragma unroll
  for (int j = 0; j < 4; ++j) { ha[j] = f2b(a[j]); hb[j] = f2b(b[j]); }
  *reinterpret_cast<us4*>(oWk + i) = ha;
  *reinterpret_cast<us4*>(oWv + i) = hb;
}

// ---------------- K1: S = Wk*x (bf16 MFMA) + fused row partial expsums -----
// Epilogue computes exp(bf16(S)) (bit-identical to k3's read), reduces over
// the block's 128 n (in-wave shfl over lr + cross-wave LDS), writes
// psum[b][nblk][m] (coalesced). Deterministic (no atomics).
#define K1_XPAD 72

__global__ __launch_bounds__(256) void k1_gemm1(
    const float* __restrict__ gx, const unsigned short* __restrict__ gWkB,
    unsigned short* __restrict__ gS, float* __restrict__ gPsum) {
  __shared__ unsigned short Wk_s[128 * 64];        // [m][c] linear, swizzled
  __shared__ unsigned short xT_s[128 * K1_XPAD];   // [n][c] padded
  __shared__ float rsum2[2][128];
  const int t = threadIdx.x;
  const int b = blockIdx.z;
  const int m0 = blockIdx.y * 128;
  const int n0 = blockIdx.x * 128;
  const int w = t >> 6;
  const int lane = t & 63;
  const int lr = lane & 15;
  const int lg = lane >> 4;
  const int wm = (w >> 1) * 64;
  const int wn = (w & 1) * 64;

  f32x4 acc[4][4] = {};
  const float* xb = gx + (size_t)b * Cdim * Ndim + n0;

  const int snl = t & 63;          // staging: n within half-tile
  const int scb = (t >> 6) * 16;   // staging: c block (wave-uniform)
  const int wrow = lane >> 3;
  const int wchk = (lane & 7) ^ (wrow & 7);

  for (int ck = 0; ck < Cdim; ck += 64) {
    {
      const unsigned short* gsrc =
          gWkB + (size_t)(m0 + w * 32 + wrow) * Cdim + ck + wchk * 8;
#pragma unroll
      for (int j = 0; j < 4; ++j) {
        __builtin_amdgcn_global_load_lds(
            (const __attribute__((address_space(1))) unsigned int*)(gsrc + (size_t)j * 8 * Cdim),
            (__attribute__((address_space(3))) unsigned int*)&Wk_s[(w * 32 + j * 8) * 64],
            16, 0, 0);
      }
    }
#pragma unroll
    for (int h = 0; h < 2; ++h) {
      const int n = snl + h * 64;
      const float* src = xb + (size_t)(ck + scb) * Ndim + n;
      float xv[16];
#pragma unroll
      for (int j = 0; j < 16; ++j) xv[j] = src[(size_t)j * Ndim];
      us8 h0, h1;
#pragma unroll
      for (int j = 0; j < 8; ++j) {
        h0[j] = (unsigned short)(__float_as_uint(xv[j]) >> 16);
        h1[j] = (unsigned short)(__float_as_uint(xv[8 + j]) >> 16);
      }
      *reinterpret_cast<us8*>(&xT_s[n * K1_XPAD + scb]) = h0;
      *reinterpret_cast<us8*>(&xT_s[n * K1_XPAD + scb + 8]) = h1;
    }
    __syncthreads();
#pragma unroll
    for (int kk = 0; kk < 64; kk += 32) {
      bf16x8 af[4], bfr[4];
#pragma unroll
      for (int mi = 0; mi < 4; ++mi) {
        const int rm = wm + mi * 16 + lr;
        af[mi] = *reinterpret_cast<const bf16x8*>(
            reinterpret_cast<const char*>(Wk_s) +
            rm * 128 + ((kk * 2 + lg * 16) ^ ((rm & 7) << 4)));
      }
#pragma unroll
      for (int ni = 0; ni < 4; ++ni)
        bfr[ni] = *reinterpret_cast<const bf16x8*>(
            &xT_s[(wn + ni * 16 + lr) * K1_XPAD + kk + lg * 8]);
#pragma unroll
      for (int mi = 0; mi < 4; ++mi)
#pragma unroll
        for (int ni = 0; ni < 4; ++ni)
          acc[mi][ni] = __builtin_amdgcn_mfma_f32_16x16x32_bf16(
              af[mi], bfr[ni], acc[mi][ni], 0, 0, 0);
    }
    __syncthreads();
  }
  // epilogue: store S (bf16) and accumulate row partial sums of exp(bf16 S)
  unsigned short* Sb = gS + ((size_t)b * Mdim + m0 + wm) * Ndim + n0 + wn;
#pragma unroll
  for (int mi = 0; mi < 4; ++mi)
#pragma unroll
    for (int r = 0; r < 4; ++r) {
      float s = 0.f;
#pragma unroll
      for (int ni = 0; ni < 4; ++ni) {
        const unsigned short h = f2b(acc[mi][ni][r]);
        const int m = mi * 16 + lg * 4 + r;
        const int n = ni * 16 + lr;
        Sb[(size_t)m * Ndim + n] = h;
        s += __expf(b2f(h));
      }
#pragma unroll
      for (int o = 1; o < 16; o <<= 1) s += __shfl_xor(s, o, 64);
      if (lr == 0) rsum2[w & 1][wm + mi * 16 + lg * 4 + r] = s;
    }
  __syncthreads();
  if (t < 128)
    gPsum[((size_t)b * 32 + blockIdx.x) * Mdim + m0 + t] =
        rsum2[0][t] + rsum2[1][t];
}

// ---------------- K2r: rinv[b][m] = 1 / sum_nblk psum ----------------------
__global__ __launch_bounds__(256) void k2_reduce(
    const float* __restrict__ gPsum, float* __restrict__ stats) {
  const int b = blockIdx.x;
  const int m = threadIdx.x;
  float s = 0.f;
#pragma unroll
  for (int nb = 0; nb < 32; ++nb)
    s += gPsum[((size_t)b * 32 + nb) * Mdim + m];
  stats[b * Mdim + m] = 1.0f / s;
}

// ---------------- K3: softmax + L1-normalize over M, write PT[b][n][m] -----
#define K3_PAD 264

__global__ __launch_bounds__(256) void k3_norm(
    const unsigned short* __restrict__ gS, const float* __restrict__ stats,
    unsigned short* __restrict__ gPT) {
  __shared__ unsigned short P_s[64 * K3_PAD];
  __shared__ float cs[4][64];
  __shared__ float rtot[64];
  const int b = blockIdx.y;
  const int n0 = blockIdx.x * 64;
  const int t = threadIdx.x;
  const int w = t >> 6;
  const int l = t & 63;
  const unsigned short* Sb = gS + ((size_t)b * Mdim + w * 64) * Ndim + n0 + l;
  const float* stb = stats + (size_t)b * Mdim + w * 64;
  float acc = 0.f;
#pragma unroll
  for (int i8 = 0; i8 < 8; ++i8) {
    us8 pk;
#pragma unroll
    for (int jj = 0; jj < 8; ++jj) {
      const int mi = i8 * 8 + jj;
      float p = __expf(b2f(Sb[(size_t)mi * Ndim])) * stb[mi];
      acc += p;
      pk[jj] = f2b(p);
    }
    *reinterpret_cast<us8*>(&P_s[l * K3_PAD + w * 64 + i8 * 8]) = pk;
  }
  cs[w][l] = acc;
  __syncthreads();
  if (w == 0) rtot[l] = 1.0f / (1e-9f + cs[0][l] + cs[1][l] + cs[2][l] + cs[3][l]);
  __syncthreads();
  const int mo = (t & 31) * 8;
#pragma unroll
  for (int j = 0; j < 8; ++j) {
    const int n = (t >> 5) + j * 8;
    const float rc = rtot[n];
    us8 pv = *reinterpret_cast<const us8*>(&P_s[n * K3_PAD + mo]);
    us8 o;
#pragma unroll
    for (int q = 0; q < 8; ++q) o[q] = f2b(b2f(pv[q]) * rc);
    *reinterpret_cast<us8*>(gPT + ((size_t)b * Ndim + n0 + n) * Mdim + mo) = o;
  }
}

// ---------------- K4: out = x + Wv * Pn  (64n x 128c, T14 async-stage) -----
// Same 64n x 128c tile / pad-136 conflict-free geometry; the two K-chunks
// are unrolled with chunk-1's global loads ISSUED before chunk-0's MFMA
// phase (write to LDS after the post-compute barrier) -> HBM/L2 latency
// hides under compute. 3 barriers total.
#define K4_P 136

__global__ __launch_bounds__(256) void k4_gemm2(
    const float* __restrict__ gx, const unsigned short* __restrict__ gWvB,
    const unsigned short* __restrict__ gPT, float* __restrict__ gout) {
  __shared__ unsigned short Wv_s[128 * K4_P];
  __shared__ unsigned short PT_s[64 * K4_P];
  const int t = threadIdx.x;
  const int b = blockIdx.z;
  const int c0 = blockIdx.y * 128;
  const int n0 = blockIdx.x * 64;
  const int w = t >> 6;
  const int lane = t & 63;
  const int lr = lane & 15;
  const int lg = lane >> 4;
  const int wc = (w >> 1) * 64;   // wave c-offset (2 waves in c)
  const int wn = (w & 1) * 32;    // wave n-offset (2 waves in n)

  const int sr = t >> 4;          // staging row helper (0..15)
  const int smq = (t & 15) * 8;   // staging m-offset (shorts)

  f32x4 acc[4][2] = {};

  us8 wv_r[8], pt_r[4];
  // ---- load chunk 0 (ck=0) to regs
#pragma unroll
  for (int i = 0; i < 8; ++i)
    wv_r[i] = *reinterpret_cast<const us8*>(
        gWvB + (size_t)(c0 + i * 16 + sr) * Mdim + smq);
#pragma unroll
  for (int i = 0; i < 4; ++i)
    pt_r[i] = *reinterpret_cast<const us8*>(
        gPT + ((size_t)b * Ndim + n0 + i * 16 + sr) * Mdim + smq);
  // ---- write chunk 0 to LDS
#pragma unroll
  for (int i = 0; i < 8; ++i)
    *reinterpret_cast<us8*>(&Wv_s[(i * 16 + sr) * K4_P + smq]) = wv_r[i];
#pragma unroll
  for (int i = 0; i < 4; ++i)
    *reinterpret_cast<us8*>(&PT_s[(i * 16 + sr) * K4_P + smq]) = pt_r[i];
  __syncthreads();

  // ---- issue chunk 1 (ck=128) loads to regs (hidden under chunk-0 MFMA)
  us8 wv2_r[8], pt2_r[4];
#pragma unroll
  for (int i = 0; i < 8; ++i)
    wv2_r[i] = *reinterpret_cast<const us8*>(
        gWvB + (size_t)(c0 + i * 16 + sr) * Mdim + 128 + smq);
#pragma unroll
  for (int i = 0; i < 4; ++i)
    pt2_r[i] = *reinterpret_cast<const us8*>(
        gPT + ((size_t)b * Ndim + n0 + i * 16 + sr) * Mdim + 128 + smq);

  // ---- compute chunk 0
#pragma unroll
  for (int kk = 0; kk < 128; kk += 32) {
    bf16x8 af[4], bfr[2];
#pragma unroll
    for (int ci = 0; ci < 4; ++ci)
      af[ci] = *reinterpret_cast<const bf16x8*>(
          &Wv_s[(wc + ci * 16 + lr) * K4_P + kk + lg * 8]);
#pragma unroll
    for (int ni = 0; ni < 2; ++ni)
      bfr[ni] = *reinterpret_cast<const bf16x8*>(
          &PT_s[(wn + ni * 16 + lr) * K4_P + kk + lg * 8]);
#pragma unroll
    for (int ci = 0; ci < 4; ++ci)
#pragma unroll
      for (int ni = 0; ni < 2; ++ni)
        acc[ci][ni] = __builtin_amdgcn_mfma_f32_16x16x32_bf16(
            af[ci], bfr[ni], acc[ci][ni], 0, 0, 0);
  }
  __syncthreads();

  // ---- write chunk 1 to LDS
#pragma unroll
  for (int i = 0; i < 8; ++i)
    *reinterpret_cast<us8*>(&Wv_s[(i * 16 + sr) * K4_P + smq]) = wv2_r[i];
#pragma unroll
  for (int i = 0; i < 4; ++i)
    *reinterpret_cast<us8*>(&PT_s[(i * 16 + sr) * K4_P + smq]) = pt2_r[i];
  __syncthreads();

  // ---- compute chunk 1
#pragma unroll
  for (int kk = 0; kk < 128; kk += 32) {
    bf16x8 af[4], bfr[2];
#pragma unroll
    for (int ci = 0; ci < 4; ++ci)
      af[ci] = *reinterpret_cast<const bf16x8*>(
          &Wv_s[(wc + ci * 16 + lr) * K4_P + kk + lg * 8]);
#pragma unroll
    for (int ni = 0; ni < 2; ++ni)
      bfr[ni] = *reinterpret_cast<const bf16x8*>(
          &PT_s[(wn + ni * 16 + lr) * K4_P + kk + lg * 8]);
#pragma unroll
    for (int ci = 0; ci < 4; ++ci)
#pragma unroll
      for (int ni = 0; ni < 2; ++ni)
        acc[ci][ni] = __builtin_amdgcn_mfma_f32_16x16x32_bf16(
            af[ci], bfr[ni], acc[ci][ni], 0, 0, 0);
  }

#pragma unroll
  for (int ci = 0; ci < 4; ++ci)
#pragma unroll
    for (int ni = 0; ni < 2; ++ni)
#pragma unroll
      for (int r = 0; r < 4; ++r) {
        int c = c0 + wc + ci * 16 + lg * 4 + r;
        int n = n0 + wn + ni * 16 + lr;
        size_t idx = ((size_t)b * Cdim + c) * Ndim + n;
        gout[idx] = gx[idx] + acc[ci][ni][r];
      }
}

extern "C" void kernel_launch(void* const* d_in, const int* in_sizes, int n_in,
                              void* d_out, int out_size, void* d_ws, size_t ws_size,
                              hipStream_t stream) {
  const float* x = (const float*)d_in[0];
  const float* Wk = (const float*)d_in[1];
  const float* Wv = (const float*)d_in[2];
  float* out = (float*)d_out;

  unsigned short* S = (unsigned short*)d_ws;                    // [B][M][N] bf16
  unsigned short* PT = S + (size_t)Bdim * Mdim * Ndim;          // [B][N][M] bf16
  float* stats = (float*)(PT + (size_t)Bdim * Ndim * Mdim);     // [B][M] rinv
  float* psum = stats + Bdim * Mdim;                            // [B][32][M]
  unsigned short* WkB = (unsigned short*)(psum + Bdim * 32 * Mdim); // [M][C]
  unsigned short* WvB = WkB + Mdim * Cdim;                      // [C][M] bf16

  k0_convert<<<dim3((Mdim * Cdim) / 1024), 256, 0, stream>>>(Wk, Wv, WkB, WvB);
  k1_gemm1<<<dim3(Ndim / 128, Mdim / 128, Bdim), 256, 0, stream>>>(x, WkB, S, psum);
  k2_reduce<<<dim3(Bdim), 256, 0, stream>>>(psum, stats);
  k3_norm<<<dim3(Ndim / 64, Bdim), 256, 0, stream>>>(S, stats, PT);
  k4_gemm2<<<dim3(Ndim / 64, Cdim / 128, Bdim), 256, 0, stream>>>(x, WvB, PT, out);
}

// Round 14
// 122.911 us; speedup vs baseline: 1.0382x; 1.0382x over previous
//
#include <hip/hip_runtime.h>
#include <hip/hip_bf16.h>

#define Bdim 16
#define Cdim 512
#define Mdim 256
#define Ndim 4096

typedef short bf16x8 __attribute__((ext_vector_type(8)));
typedef float f32x4 __attribute__((ext_vector_type(4)));
typedef unsigned short us8 __attribute__((ext_vector_type(8)));
typedef unsigned short us4 __attribute__((ext_vector_type(4)));

// round-half-up f32 -> bf16 (tie bias only vs RNE)
__device__ __forceinline__ unsigned short f2b(float f) {
  union { float f; unsigned int u; } v; v.f = f;
  return (unsigned short)((v.u + 0x8000u) >> 16);
}
__device__ __forceinline__ float b2f(unsigned short h) {
  union { unsigned int u; float f; } v; v.u = ((unsigned int)h) << 16;
  return v.f;
}

// ---------------- K0: one-time Wk,Wv f32 -> bf16 (512 KB total) -----------
__global__ __launch_bounds__(256) void k0_convert(
    const float* __restrict__ gWk, const float* __restrict__ gWv,
    unsigned short* __restrict__ oWk, unsigned short* __restrict__ oWv) {
  const int i = (blockIdx.x * 256 + threadIdx.x) * 4;
  f32x4 a = *reinterpret_cast<const f32x4*>(gWk + i);
  f32x4 b = *reinterpret_cast<const f32x4*>(gWv + i);
  us4 ha, hb;
#pragma unroll
  for (int j = 0; j < 4; ++j) { ha[j] = f2b(a[j]); hb[j] = f2b(b[j]); }
  *reinterpret_cast<us4*>(oWk + i) = ha;
  *reinterpret_cast<us4*>(oWv + i) = hb;
}

// ---------------- K1: S[b,m,n] = sum_c Wk[m,c] * x[b,c,n]  (bf16 MFMA) ----
// x staging rebuilt: per thread a 4c x 4n block via 4 coalesced f32x4 loads,
// in-register 4x4 transpose, 4x ds_write_b64 into [n][72]-shorts LDS with
// 16B-granule XOR swizzle  byte = n*144 + ((c*2) ^ (((n>>2)&7)<<4)).
// Verified: writes <=4-way (cheap), b128 fragment reads 2-way (free).
// Wk path unchanged: global_load_lds into linear [m][64] with source
// pre-swizzle (chunk ^= row&7), swizzled b128 reads.
__global__ __launch_bounds__(256) void k1_gemm1(
    const float* __restrict__ gx, const unsigned short* __restrict__ gWkB,
    unsigned short* __restrict__ gS) {
  __shared__ unsigned short Wk_s[128 * 64];   // [m][c] linear, swizzled
  __shared__ unsigned short xT_s[128 * 72];   // [n][c] XOR-swizzled
  const int t = threadIdx.x;
  const int b = blockIdx.z;
  const int m0 = blockIdx.y * 128;
  const int n0 = blockIdx.x * 128;
  const int w = t >> 6;
  const int lane = t & 63;
  const int lr = lane & 15;
  const int lg = lane >> 4;
  const int wm = (w >> 1) * 64;
  const int wn = (w & 1) * 64;

  f32x4 acc[4][4] = {};
  const float* xb = gx + (size_t)b * Cdim * Ndim + n0;

  const int nq = t & 31;    // n-quad (0..31) -> n = nq*4
  const int cq0 = t >> 5;   // c-quad (0..7); second pass +8
  const int wrow = lane >> 3;
  const int wchk = (lane & 7) ^ (wrow & 7);

  for (int ck = 0; ck < Cdim; ck += 64) {
    // --- Wk[m0+w*32..+32][ck..+63] -> Wk_s via global_load_lds
    {
      const unsigned short* gsrc =
          gWkB + (size_t)(m0 + w * 32 + wrow) * Cdim + ck + wchk * 8;
#pragma unroll
      for (int j = 0; j < 4; ++j) {
        __builtin_amdgcn_global_load_lds(
            (const __attribute__((address_space(1))) unsigned int*)(gsrc + (size_t)j * 8 * Cdim),
            (__attribute__((address_space(3))) unsigned int*)&Wk_s[(w * 32 + j * 8) * 64],
            16, 0, 0);
      }
    }
    // --- x[ck..+63][n0..+127] -> xT_s (transposed): 4c x 4n reg blocks
#pragma unroll
    for (int p = 0; p < 2; ++p) {
      const int cb = (cq0 + p * 8) * 4;   // c within chunk (0..60)
      const float* src = xb + (size_t)(ck + cb) * Ndim + nq * 4;
      f32x4 v[4];
#pragma unroll
      for (int j = 0; j < 4; ++j)
        v[j] = *reinterpret_cast<const f32x4*>(src + (size_t)j * Ndim);
      char* dst = reinterpret_cast<char*>(xT_s) + ((cb * 2) ^ ((nq & 7) << 4));
#pragma unroll
      for (int k = 0; k < 4; ++k) {
        us4 h;
#pragma unroll
        for (int j = 0; j < 4; ++j)
          h[j] = (unsigned short)(__float_as_uint(v[j][k]) >> 16);
        *reinterpret_cast<us4*>(dst + (nq * 4 + k) * 144) = h;
      }
    }
    __syncthreads();
#pragma unroll
    for (int kk = 0; kk < 64; kk += 32) {
      bf16x8 af[4], bfr[4];
#pragma unroll
      for (int mi = 0; mi < 4; ++mi) {
        const int rm = wm + mi * 16 + lr;
        af[mi] = *reinterpret_cast<const bf16x8*>(
            reinterpret_cast<const char*>(Wk_s) +
            rm * 128 + ((kk * 2 + lg * 16) ^ ((rm & 7) << 4)));
      }
#pragma unroll
      for (int ni = 0; ni < 4; ++ni) {
        const int rn = wn + ni * 16 + lr;
        bfr[ni] = *reinterpret_cast<const bf16x8*>(
            reinterpret_cast<const char*>(xT_s) +
            rn * 144 + ((kk * 2 + lg * 16) ^ (((rn >> 2) & 7) << 4)));
      }
#pragma unroll
      for (int mi = 0; mi < 4; ++mi)
#pragma unroll
        for (int ni = 0; ni < 4; ++ni)
          acc[mi][ni] = __builtin_amdgcn_mfma_f32_16x16x32_bf16(
              af[mi], bfr[ni], acc[mi][ni], 0, 0, 0);
    }
    __syncthreads();
  }
  unsigned short* Sb = gS + ((size_t)b * Mdim + m0 + wm) * Ndim + n0 + wn;
#pragma unroll
  for (int mi = 0; mi < 4; ++mi)
#pragma unroll
    for (int ni = 0; ni < 4; ++ni)
#pragma unroll
      for (int r = 0; r < 4; ++r) {
        int m = mi * 16 + lg * 4 + r;
        int n = ni * 16 + lr;
        Sb[(size_t)m * Ndim + n] = f2b(acc[mi][ni][r]);
      }
}

// ---------------- K2: per-(b,m) rinv = 1/sum(exp(S)) (no-max: |S|<~6) ------
__global__ __launch_bounds__(256) void k2_rowstats(
    const unsigned short* __restrict__ gS, float* __restrict__ stats) {
  const int m = blockIdx.x;
  const int b = blockIdx.y;
  const unsigned short* row = gS + ((size_t)b * Mdim + m) * Ndim;
  const int t = threadIdx.x;
  const int w = t >> 6;
  float s = 0.f;
#pragma unroll
  for (int i = 0; i < 2; ++i) {
    us8 u = *reinterpret_cast<const us8*>(row + i * 2048 + t * 8);
#pragma unroll
    for (int j = 0; j < 8; ++j) s += __expf(b2f(u[j]));
  }
#pragma unroll
  for (int o = 32; o > 0; o >>= 1) s += __shfl_xor(s, o, 64);
  __shared__ float redsum[4];
  if ((t & 63) == 0) redsum[w] = s;
  __syncthreads();
  if (t == 0) {
    float tot = redsum[0] + redsum[1] + redsum[2] + redsum[3];
    stats[(size_t)b * Mdim + m] = 1.0f / tot;
  }
}

// ---------------- K3: softmax + L1-normalize over M, write PT[b][n][m] -----
#define K3_PAD 264

__global__ __launch_bounds__(256) void k3_norm(
    const unsigned short* __restrict__ gS, const float* __restrict__ stats,
    unsigned short* __restrict__ gPT) {
  __shared__ unsigned short P_s[64 * K3_PAD];
  __shared__ float cs[4][64];
  __shared__ float rtot[64];
  const int b = blockIdx.y;
  const int n0 = blockIdx.x * 64;
  const int t = threadIdx.x;
  const int w = t >> 6;
  const int l = t & 63;
  const unsigned short* Sb = gS + ((size_t)b * Mdim + w * 64) * Ndim + n0 + l;
  const float* stb = stats + (size_t)b * Mdim + w * 64;
  float acc = 0.f;
#pragma unroll
  for (int i8 = 0; i8 < 8; ++i8) {
    us8 pk;
#pragma unroll
    for (int jj = 0; jj < 8; ++jj) {
      const int mi = i8 * 8 + jj;
      float p = __expf(b2f(Sb[(size_t)mi * Ndim])) * stb[mi];
      acc += p;
      pk[jj] = f2b(p);
    }
    *reinterpret_cast<us8*>(&P_s[l * K3_PAD + w * 64 + i8 * 8]) = pk;
  }
  cs[w][l] = acc;
  __syncthreads();
  if (w == 0) rtot[l] = 1.0f / (1e-9f + cs[0][l] + cs[1][l] + cs[2][l] + cs[3][l]);
  __syncthreads();
  const int mo = (t & 31) * 8;
#pragma unroll
  for (int j = 0; j < 8; ++j) {
    const int n = (t >> 5) + j * 8;
    const float rc = rtot[n];
    us8 pv = *reinterpret_cast<const us8*>(&P_s[n * K3_PAD + mo]);
    us8 o;
#pragma unroll
    for (int q = 0; q < 8; ++q) o[q] = f2b(b2f(pv[q]) * rc);
    *reinterpret_cast<us8*>(gPT + ((size_t)b * Ndim + n0 + n) * Mdim + mo) = o;
  }
}

// ---------------- K4: out = x + Wv * Pn  (64n x 128c tile, R12 version) ----
#define K4_P 136

__global__ __launch_bounds__(256) void k4_gemm2(
    const float* __restrict__ gx, const unsigned short* __restrict__ gWvB,
    const unsigned short* __restrict__ gPT, float* __restrict__ gout) {
  __shared__ unsigned short Wv_s[128 * K4_P];
  __shared__ unsigned short PT_s[64 * K4_P];
  const int t = threadIdx.x;
  const int b = blockIdx.z;
  const int c0 = blockIdx.y * 128;
  const int n0 = blockIdx.x * 64;
  const int w = t >> 6;
  const int lane = t & 63;
  const int lr = lane & 15;
  const int lg = lane >> 4;
  const int wc = (w >> 1) * 64;   // wave c-offset (2 waves in c)
  const int wn = (w & 1) * 32;    // wave n-offset (2 waves in n)

  f32x4 acc[4][2] = {};

  for (int ck = 0; ck < Mdim; ck += 128) {
    // stage Wv[c0..+127][ck..+127] (bf16, us8 vector loads)
#pragma unroll
    for (int i = 0; i < 8; ++i) {
      int q = i * 256 + t;
      int r = q >> 4;
      int mq = (q & 15) * 8;
      us8 u = *reinterpret_cast<const us8*>(gWvB + (size_t)(c0 + r) * Mdim + ck + mq);
      *reinterpret_cast<us8*>(&Wv_s[r * K4_P + mq]) = u;
    }
    // stage PT[b][n0..+63][ck..+127] (bf16)
#pragma unroll
    for (int i = 0; i < 4; ++i) {
      int q = i * 256 + t;
      int r = q >> 4;
      int mq = (q & 15) * 8;
      us8 u = *reinterpret_cast<const us8*>(gPT + ((size_t)b * Ndim + n0 + r) * Mdim + ck + mq);
      *reinterpret_cast<us8*>(&PT_s[r * K4_P + mq]) = u;
    }
    __syncthreads();
#pragma unroll
    for (int kk = 0; kk < 128; kk += 32) {
      bf16x8 af[4], bfr[2];
#pragma unroll
      for (int ci = 0; ci < 4; ++ci)
        af[ci] = *reinterpret_cast<const bf16x8*>(
            &Wv_s[(wc + ci * 16 + lr) * K4_P + kk + lg * 8]);
#pragma unroll
      for (int ni = 0; ni < 2; ++ni)
        bfr[ni] = *reinterpret_cast<const bf16x8*>(
            &PT_s[(wn + ni * 16 + lr) * K4_P + kk + lg * 8]);
#pragma unroll
      for (int ci = 0; ci < 4; ++ci)
#pragma unroll
        for (int ni = 0; ni < 2; ++ni)
          acc[ci][ni] = __builtin_amdgcn_mfma_f32_16x16x32_bf16(
              af[ci], bfr[ni], acc[ci][ni], 0, 0, 0);
    }
    __syncthreads();
  }
#pragma unroll
  for (int ci = 0; ci < 4; ++ci)
#pragma unroll
    for (int ni = 0; ni < 2; ++ni)
#pragma unroll
      for (int r = 0; r < 4; ++r) {
        int c = c0 + wc + ci * 16 + lg * 4 + r;
        int n = n0 + wn + ni * 16 + lr;
        size_t idx = ((size_t)b * Cdim + c) * Ndim + n;
        gout[idx] = gx[idx] + acc[ci][ni][r];
      }
}

extern "C" void kernel_launch(void* const* d_in, const int* in_sizes, int n_in,
                              void* d_out, int out_size, void* d_ws, size_t ws_size,
                              hipStream_t stream) {
  const float* x = (const float*)d_in[0];
  const float* Wk = (const float*)d_in[1];
  const float* Wv = (const float*)d_in[2];
  float* out = (float*)d_out;

  unsigned short* S = (unsigned short*)d_ws;                    // [B][M][N] bf16
  unsigned short* PT = S + (size_t)Bdim * Mdim * Ndim;          // [B][N][M] bf16
  float* stats = (float*)(PT + (size_t)Bdim * Ndim * Mdim);     // [B][M] rinv
  unsigned short* WkB = (unsigned short*)(stats + Bdim * Mdim); // [M][C] bf16
  unsigned short* WvB = WkB + Mdim * Cdim;                      // [C][M] bf16

  k0_convert<<<dim3((Mdim * Cdim) / 1024), 256, 0, stream>>>(Wk, Wv, WkB, WvB);
  k1_gemm1<<<dim3(Ndim / 128, Mdim / 128, Bdim), 256, 0, stream>>>(x, WkB, S);
  k2_rowstats<<<dim3(Mdim, Bdim), 256, 0, stream>>>(S, stats);
  k3_norm<<<dim3(Ndim / 64, Bdim), 256, 0, stream>>>(S, stats, PT);
  k4_gemm2<<<dim3(Ndim / 64, Cdim / 128, Bdim), 256, 0, stream>>>(x, WvB, PT, out);
}